// Round 12
// baseline (178.988 us; speedup 1.0000x reference)
//
#include <hip/hip_runtime.h>
#include <hip/hip_bf16.h>
#include <math.h>

#define N_TOK 4096

typedef __attribute__((ext_vector_type(8))) short short8;
typedef __attribute__((ext_vector_type(4))) float f32x4;

#define MFMA16(a, b, c) __builtin_amdgcn_mfma_f32_16x16x32_bf16(a, b, c, 0, 0, 0)

__device__ inline unsigned pack_bf16x2(float a, float b) {
    __hip_bfloat16 ha = __float2bfloat16(a), hb = __float2bfloat16(b);
    unsigned short ua = *(unsigned short*)&ha, ub = *(unsigned short*)&hb;
    return (unsigned)ua | ((unsigned)ub << 16);
}

__device__ inline float bf2f(unsigned short u) {
    unsigned v = ((unsigned)u) << 16;
    union { unsigned u; float f; } cv; cv.u = v; return cv.f;
}

// swizzled 16B-chunk slot for row-stride-64B LDS tiles (<=2-way conflicts)
__device__ inline int swz4(int h, int row) { return (h ^ row ^ (row >> 2)) & 3; }

// scale * log2(e), folded into q at projection time
#define SCK 0.25506974748975505f

// ---------------------------------------------------------------------------
// x (B,C,N) f32 -> xt (B,N,C) bf16  (transpose + convert)
// ---------------------------------------------------------------------------
__global__ __launch_bounds__(256) void xt_prep_kernel(
    const float* __restrict__ x, __hip_bfloat16* __restrict__ xt)
{
    __shared__ __hip_bfloat16 tl[64][72];   // [n][c] pad 8
    int blk = blockIdx.x;
    int cg = blk & 3, ng = (blk >> 2) & 63, b = blk >> 8;
    int n0 = ng * 64, c0 = cg * 64;
    int t = threadIdx.x;
    int cr = t >> 4, part = t & 15;
#pragma unroll
    for (int rep = 0; rep < 4; ++rep) {
        int c = rep * 16 + cr;
        float4 v4 = *(const float4*)&x[((size_t)(b * 256 + c0 + c)) * N_TOK + n0 + part * 4];
        tl[part * 4 + 0][c] = __float2bfloat16(v4.x);
        tl[part * 4 + 1][c] = __float2bfloat16(v4.y);
        tl[part * 4 + 2][c] = __float2bfloat16(v4.z);
        tl[part * 4 + 3][c] = __float2bfloat16(v4.w);
    }
    __syncthreads();
    int n = t >> 2, g = t & 3;
    uint4 u0 = *(uint4*)&tl[n][g * 16];
    uint4 u1 = *(uint4*)&tl[n][g * 16 + 8];
    __hip_bfloat16* dst = &xt[((size_t)(b * N_TOK + n0 + n)) * 256 + c0 + g * 16];
    *(uint4*)dst = u0;
    *(uint4*)&dst[8] = u1;
}

// ---------------------------------------------------------------------------
// Weight prep: Wo->Wt[tap][o][c] bf16 ; Wq,Wk->Wqk[64][256] ; Wv->Wvb bf16
// ---------------------------------------------------------------------------
__global__ __launch_bounds__(256) void w_prep_kernel(
    const float* __restrict__ Wo, const float* __restrict__ Wq,
    const float* __restrict__ Wk, const float* __restrict__ Wv,
    __hip_bfloat16* __restrict__ Wt, __hip_bfloat16* __restrict__ Wqk,
    __hip_bfloat16* __restrict__ Wvb)
{
    int blk = blockIdx.x, t = threadIdx.x;
    if (blk < 256) {
        const float* src = &Wo[(size_t)(blk * 256 + t) * 9];
#pragma unroll
        for (int tap = 0; tap < 9; ++tap)
            Wt[(size_t)(tap * 256 + blk) * 256 + t] = __float2bfloat16(src[tap]);
    } else if (blk < 260) {
        int r0 = (blk - 256) * 64;
        for (int r = r0; r < r0 + 64; ++r)
            Wvb[r * 256 + t] = __float2bfloat16(Wv[r * 256 + t]);
    } else {
        for (int r = 0; r < 32; ++r) {
            // q rows pre-scaled by SCK (softmax scale * log2e folded in)
            Wqk[r * 256 + t]        = __float2bfloat16(Wq[r * 256 + t] * SCK);
            Wqk[(r + 32) * 256 + t] = __float2bfloat16(Wk[r * 256 + t]);
        }
    }
}

// ---------------------------------------------------------------------------
// QK projection via MFMA -> qg,kg (B,N,32). q side pre-scaled by SCK.
// ---------------------------------------------------------------------------
__global__ __launch_bounds__(256) void qk_mfma_kernel(
    const __hip_bfloat16* __restrict__ xt, const __hip_bfloat16* __restrict__ Wqk,
    const float* __restrict__ bq, const float* __restrict__ bk,
    __hip_bfloat16* __restrict__ qg, __hip_bfloat16* __restrict__ kg)
{
    int blk = blockIdx.x;
    int b = blk >> 6, n0 = (blk & 63) * 64;
    int t = threadIdx.x, w = t >> 6, lane = t & 63;
    int l15 = lane & 15, l4 = lane >> 4;
    int n = n0 + w * 16 + l15;

    f32x4 zf = {0.f, 0.f, 0.f, 0.f};
    f32x4 acc[4];
#pragma unroll
    for (int m = 0; m < 4; ++m) acc[m] = zf;

    const __hip_bfloat16* xrow = &xt[((size_t)(b * N_TOK + n)) * 256];
    for (int k0 = 0; k0 < 256; k0 += 32) {
        short8 bfr = *(const short8*)&xrow[k0 + l4 * 8];
#pragma unroll
        for (int m = 0; m < 4; ++m) {
            short8 af = *(const short8*)&Wqk[(size_t)(m * 16 + l15) * 256 + k0 + l4 * 8];
            acc[m] = MFMA16(af, bfr, acc[m]);
        }
    }
    f32x4 bq0 = *(const f32x4*)&bq[l4 * 4];
    f32x4 bq1 = *(const f32x4*)&bq[16 + l4 * 4];
    f32x4 bk0 = *(const f32x4*)&bk[l4 * 4];
    f32x4 bk1 = *(const f32x4*)&bk[16 + l4 * 4];
    size_t obase = (size_t)(b * N_TOK + n) * 32;
    uint2 u;
    u.x = pack_bf16x2(acc[0][0] + bq0[0] * SCK, acc[0][1] + bq0[1] * SCK);
    u.y = pack_bf16x2(acc[0][2] + bq0[2] * SCK, acc[0][3] + bq0[3] * SCK);
    *(uint2*)&qg[obase + l4 * 4] = u;
    u.x = pack_bf16x2(acc[1][0] + bq1[0] * SCK, acc[1][1] + bq1[1] * SCK);
    u.y = pack_bf16x2(acc[1][2] + bq1[2] * SCK, acc[1][3] + bq1[3] * SCK);
    *(uint2*)&qg[obase + 16 + l4 * 4] = u;
    u.x = pack_bf16x2(acc[2][0] + bk0[0], acc[2][1] + bk0[1]);
    u.y = pack_bf16x2(acc[2][2] + bk0[2], acc[2][3] + bk0[3]);
    *(uint2*)&kg[obase + l4 * 4] = u;
    u.x = pack_bf16x2(acc[3][0] + bk1[0], acc[3][1] + bk1[1]);
    u.y = pack_bf16x2(acc[3][2] + bk1[2], acc[3][3] + bk1[3]);
    *(uint2*)&kg[obase + 16 + l4 * 4] = u;
}

// ---------------------------------------------------------------------------
// V projection via MFMA -> vg (B,C,N) bf16
// ---------------------------------------------------------------------------
__global__ __launch_bounds__(256) void v_mfma_kernel(
    const __hip_bfloat16* __restrict__ xt, const __hip_bfloat16* __restrict__ Wvb,
    const float* __restrict__ bv, __hip_bfloat16* __restrict__ vg)
{
    int blk = blockIdx.x;
    int b = blk >> 7, ch = (blk >> 6) & 1, n0 = (blk & 63) * 64;
    int c0 = ch * 128;
    int t = threadIdx.x, w = t >> 6, lane = t & 63;
    int l15 = lane & 15, l4 = lane >> 4;
    int n = n0 + w * 16 + l15;

    f32x4 zf = {0.f, 0.f, 0.f, 0.f};
    f32x4 acc[8];
#pragma unroll
    for (int m = 0; m < 8; ++m) acc[m] = zf;

    const __hip_bfloat16* xrow = &xt[((size_t)(b * N_TOK + n)) * 256];
    for (int k0 = 0; k0 < 256; k0 += 32) {
        short8 bfr = *(const short8*)&xrow[k0 + l4 * 8];
#pragma unroll
        for (int m = 0; m < 8; ++m) {
            short8 af = *(const short8*)&Wvb[(size_t)(c0 + m * 16 + l15) * 256 + k0 + l4 * 8];
            acc[m] = MFMA16(af, bfr, acc[m]);
        }
    }
#pragma unroll
    for (int m = 0; m < 8; ++m) {
        int cb = c0 + m * 16 + l4 * 4;
        f32x4 bvv = *(const f32x4*)&bv[cb];
#pragma unroll
        for (int r = 0; r < 4; ++r)
            vg[((size_t)(b * 256 + cb + r)) * N_TOK + n] = __float2bfloat16(acc[m][r] + bvv[r]);
    }
}

// ---------------------------------------------------------------------------
// Flash v9: kh=3 key-split (1408/1344/1344 keys), wave = 32q x 128c,
// block = 4 waves = 128q x 128c. grid = 4b*32qg*2cs*3kh = 768 (3 blocks/CU
// = 3 waves/SIMD). K via register prefetch (v6-proven), V dbuf in LDS,
// wave-private P. LDS 48KB. Bare-exp2 softmax (scale folded into q).
// ---------------------------------------------------------------------------
__global__ __launch_bounds__(256, 3) void flash_kernel(
    const __hip_bfloat16* __restrict__ qg, const __hip_bfloat16* __restrict__ kg,
    const __hip_bfloat16* __restrict__ vg,
    __hip_bfloat16* __restrict__ ph0, __hip_bfloat16* __restrict__ ph1,
    __hip_bfloat16* __restrict__ ph2, float* __restrict__ Lh)
{
    __shared__ __hip_bfloat16 v_lds[2][128 * 64];  // 32 KB [c][64k]
    __shared__ __hip_bfloat16 p_lds[4][32 * 64];   // 16 KB wave-private [q][64k]

    int blk = blockIdx.x;
    // XCD spread: xcd = blk&7 gets 96 consecutive work units
    int work = (blk & 7) * 96 + (blk >> 3);
    int kh = work >> 8;                     // 0..2 (256 works per kh)
    int rem = work & 255;
    int cs = rem >> 7, b = (rem >> 5) & 3, qgp = rem & 31;
    int koff  = (kh == 0) ? 0 : (kh == 1 ? 1408 : 2752);
    int iters = (kh == 0) ? 22 : 21;
    int t = threadIdx.x, w = t >> 6, lane = t & 63;
    int l15 = lane & 15, l4 = lane >> 4;
    int qw = qgp * 128 + w * 32;

    short8 qf[2];
#pragma unroll
    for (int qs = 0; qs < 2; ++qs)
        qf[qs] = *(const short8*)&qg[((size_t)(b * N_TOK + qw + qs * 16 + l15)) * 32 + l4 * 8];

    f32x4 zf = {0.f, 0.f, 0.f, 0.f};
    f32x4 acc[2][8];
#pragma unroll
    for (int qs = 0; qs < 2; ++qs)
#pragma unroll
        for (int ct = 0; ct < 8; ++ct) acc[qs][ct] = zf;
    float Lr[2] = {0.f, 0.f};

    int vc  = t >> 1;                 // V staging c-row 0..127
    int kb4 = (t & 1) * 4;            // V 16B-chunk base

    const __hip_bfloat16* vrow  = &vg[((size_t)(b * 256 + cs * 128 + vc)) * N_TOK + koff];
    const __hip_bfloat16* kbase = &kg[((size_t)(b * N_TOK + koff)) * 32];

    uint4 vp[4];
    short8 kfr[4], kfn[4];

    // prologue: V(0) -> LDS buf0, K(0) -> regs
#pragma unroll
    for (int j = 0; j < 4; ++j)
        vp[j] = *(const uint4*)&vrow[(kb4 + j) * 8];
#pragma unroll
    for (int kt = 0; kt < 4; ++kt)
        kfr[kt] = *(const short8*)&kbase[(kt * 16 + l15) * 32 + l4 * 8];
#pragma unroll
    for (int j = 0; j < 4; ++j)
        *(uint4*)&v_lds[0][vc * 64 + (((2 * (kb4 + j)) ^ (vc & 14)) << 2)] = vp[j];
    __syncthreads();

    int buf = 0;
    for (int it = 0; it < iters; ++it) {
        int nm0 = it * 64 + 64;
        bool more = (it < iters - 1);
        if (more) {
#pragma unroll
            for (int j = 0; j < 4; ++j)
                vp[j] = *(const uint4*)&vrow[nm0 + (kb4 + j) * 8];
#pragma unroll
            for (int kt = 0; kt < 4; ++kt)
                kfn[kt] = *(const short8*)&kbase[(size_t)(nm0 + kt * 16 + l15) * 32 + l4 * 8];
        }

        // ---- S^T: C[key][q], q = l15, key = kt*16 + l4*4 + r
        f32x4 sf[2][4];
#pragma unroll
        for (int qs = 0; qs < 2; ++qs)
#pragma unroll
            for (int kt = 0; kt < 4; ++kt)
                sf[qs][kt] = MFMA16(kfr[kt], qf[qs], zf);

        // ---- bare exp2 (scale folded into q; shift-free)
#pragma unroll
        for (int qs = 0; qs < 2; ++qs) {
            int prow = qs * 16 + l15;
#pragma unroll
            for (int kt = 0; kt < 4; ++kt) {
                float p0 = exp2f(sf[qs][kt][0]);
                float p1 = exp2f(sf[qs][kt][1]);
                float p2 = exp2f(sf[qs][kt][2]);
                float p3 = exp2f(sf[qs][kt][3]);
                Lr[qs] += (p0 + p1) + (p2 + p3);
                uint2 u;
                u.x = pack_bf16x2(p0, p1);
                u.y = pack_bf16x2(p2, p3);
                *(uint2*)&p_lds[w][prow * 64 + (((kt * 4 + l4) ^ (l15 & 14)) << 2)] = u;
            }
        }

        // ---- PV: A = V^T c-rows (shared across both q-subtiles)
#pragma unroll
        for (int ks = 0; ks < 2; ++ks) {
            short8 pb[2];
#pragma unroll
            for (int qs = 0; qs < 2; ++qs)
                pb[qs] = *(const short8*)&p_lds[w][(qs * 16 + l15) * 64 +
                         (((ks * 8 + l4 * 2) ^ (l15 & 14)) << 2)];
#pragma unroll
            for (int ct = 0; ct < 8; ++ct) {
                int cr = ct * 16 + l15;
                short8 vf = *(const short8*)&v_lds[buf][cr * 64 +
                           (((ks * 8 + l4 * 2) ^ (cr & 14)) << 2)];
                acc[0][ct] = MFMA16(vf, pb[0], acc[0][ct]);
                acc[1][ct] = MFMA16(vf, pb[1], acc[1][ct]);
            }
        }

        // ---- write prefetched V into other buffer, roll K
        if (more) {
#pragma unroll
            for (int j = 0; j < 4; ++j)
                *(uint4*)&v_lds[buf ^ 1][vc * 64 + (((2 * (kb4 + j)) ^ (vc & 14)) << 2)] = vp[j];
#pragma unroll
            for (int kt = 0; kt < 4; ++kt) kfr[kt] = kfn[kt];
            buf ^= 1;
        }
        __syncthreads();
    }

#pragma unroll
    for (int qs = 0; qs < 2; ++qs) {
        float L = Lr[qs];
        L += __shfl_xor(L, 16);
        L += __shfl_xor(L, 32);
        int nq = qw + qs * 16 + l15;
        if (cs == 0 && l4 == 0)
            Lh[kh * 16384 + b * 4096 + nq] = L;
        __hip_bfloat16* pdst = (kh == 0) ? ph0 : (kh == 1 ? ph1 : ph2);
        size_t pix = (size_t)(b * N_TOK + nq);
#pragma unroll
        for (int ct = 0; ct < 8; ++ct) {
            int cl = cs * 128 + ct * 16 + l4 * 4;
            uint2 u;
            u.x = pack_bf16x2(acc[qs][ct][0], acc[qs][ct][1]);
            u.y = pack_bf16x2(acc[qs][ct][2], acc[qs][ct][3]);
            *(uint2*)&pdst[pix * 256 + cl] = u;
        }
    }
}

// ---------------------------------------------------------------------------
// Linv[bn] = 1 / (Lh0 + Lh1 + Lh2)
// ---------------------------------------------------------------------------
__global__ __launch_bounds__(256) void linv_kernel(
    const float* __restrict__ Lh, float* __restrict__ Linv)
{
    int i = blockIdx.x * 256 + threadIdx.x;
    Linv[i] = 1.f / (Lh[i] + Lh[16384 + i] + Lh[32768 + i]);
}

// ---------------------------------------------------------------------------
// Implicit-GEMM 3x3 conv via MFMA + bias + BN + ReLU + residual.
// Spatial tile 16x8 (grid 512). Staging fuses the 3-way partial-combine:
// att = (ph0 + ph1 + ph2) * Linv.
// ---------------------------------------------------------------------------
__global__ __launch_bounds__(256) void conv_mfma_kernel(
    const __hip_bfloat16* __restrict__ ph0, const __hip_bfloat16* __restrict__ ph1,
    const __hip_bfloat16* __restrict__ ph2, const float* __restrict__ Linv,
    const __hip_bfloat16* __restrict__ Wt,
    const float* __restrict__ bo,  const float* __restrict__ gamma,
    const float* __restrict__ beta, const float* __restrict__ mean,
    const float* __restrict__ var, const float* __restrict__ x,
    float* __restrict__ out)
{
    __shared__ __hip_bfloat16 in_lds[180 * 32];     // [10x18 halo][32c] swz
    __shared__ __hip_bfloat16 wt_lds[9 * 64 * 32];  // [tap][o64][32c] swz

    int blk = blockIdx.x;
    int sp = blk & 31, ob = (blk >> 5) & 3, b = blk >> 7;
    int y0 = (sp >> 2) * 8, x0 = (sp & 3) * 16;
    int o0 = ob * 64;
    int t = threadIdx.x;
    int w = t >> 6, lane = t & 63;
    int l15 = lane & 15, l4 = lane >> 4;

    f32x4 zf = {0.f, 0.f, 0.f, 0.f};
    f32x4 acc[4][2];   // [m][ntw]
#pragma unroll
    for (int m = 0; m < 4; ++m)
#pragma unroll
        for (int n = 0; n < 2; ++n) acc[m][n] = zf;

    for (int cc = 0; cc < 256; cc += 32) {
        __syncthreads();
        for (int jj = t; jj < 720; jj += 256) {
            int pix = jj >> 2, h = jj & 3;
            int iy = pix / 18, ix = pix - iy * 18;
            int gy = y0 - 1 + iy, gx = x0 - 1 + ix;
            uint4 val = {0u, 0u, 0u, 0u};
            if (gy >= 0 && gy < 64 && gx >= 0 && gx < 64) {
                int bn = b * 4096 + gy * 64 + gx;
                float inv = Linv[bn];
                size_t e = (size_t)bn * 256 + cc + h * 8;
                uint4 a  = *(const uint4*)&ph0[e];
                uint4 b4 = *(const uint4*)&ph1[e];
                uint4 c4 = *(const uint4*)&ph2[e];
                const unsigned* ap = (const unsigned*)&a;
                const unsigned* bp = (const unsigned*)&b4;
                const unsigned* cp = (const unsigned*)&c4;
                unsigned* vpn = (unsigned*)&val;
#pragma unroll
                for (int j = 0; j < 4; ++j) {
                    float lo = (bf2f((unsigned short)(ap[j] & 0xffff)) +
                                bf2f((unsigned short)(bp[j] & 0xffff)) +
                                bf2f((unsigned short)(cp[j] & 0xffff))) * inv;
                    float hi = (bf2f((unsigned short)(ap[j] >> 16)) +
                                bf2f((unsigned short)(bp[j] >> 16)) +
                                bf2f((unsigned short)(cp[j] >> 16))) * inv;
                    vpn[j] = pack_bf16x2(lo, hi);
                }
            }
            *(uint4*)&in_lds[pix * 32 + swz4(h, pix) * 8] = val;
        }
        for (int jj = t; jj < 2304; jj += 256) {
            int tap = jj >> 8, rem = jj & 255;
            int o = rem >> 2, h = rem & 3;
            uint4 wv = *(const uint4*)&Wt[((size_t)(tap * 256 + o0 + o)) * 256 + cc + h * 8];
            *(uint4*)&wt_lds[tap * 2048 + o * 32 + swz4(h, o) * 8] = wv;
        }
        __syncthreads();

#pragma unroll
        for (int ky = 0; ky < 3; ++ky) {
#pragma unroll
            for (int kx = 0; kx < 3; ++kx) {
                int tap = ky * 3 + kx;
                short8 af[4];
#pragma unroll
                for (int m = 0; m < 4; ++m) {
                    int orow = m * 16 + l15;
                    af[m] = *(const short8*)&wt_lds[tap * 2048 + orow * 32 + swz4(l4, orow) * 8];
                }
#pragma unroll
                for (int ntw = 0; ntw < 2; ++ntw) {
                    int yy = w * 2 + ntw;
                    int p = (yy + ky) * 18 + kx + l15;
                    short8 bfr = *(const short8*)&in_lds[p * 32 + swz4(l4, p) * 8];
#pragma unroll
                    for (int m = 0; m < 4; ++m)
                        acc[m][ntw] = MFMA16(af[m], bfr, acc[m][ntw]);
                }
            }
        }
    }

#pragma unroll
    for (int m = 0; m < 4; ++m) {
#pragma unroll
        for (int r = 0; r < 4; ++r) {
            int oc = o0 + m * 16 + l4 * 4 + r;
            float inv = gamma[oc] * rsqrtf(var[oc] + 1e-5f);
            float sh  = (bo[oc] - mean[oc]) * inv + beta[oc];
#pragma unroll
            for (int ntw = 0; ntw < 2; ++ntw) {
                int gy = y0 + w * 2 + ntw, gx = x0 + l15;
                size_t idx = (size_t)(b * 256 + oc) * 4096 + (size_t)gy * 64 + gx;
                float yv = acc[m][ntw][r] * inv + sh;
                yv = fmaxf(yv, 0.f);
                out[idx] = yv + x[idx];
            }
        }
    }
}

// ---------------------------------------------------------------------------
extern "C" void kernel_launch(void* const* d_in, const int* in_sizes, int n_in,
                              void* d_out, int out_size, void* d_ws, size_t ws_size,
                              hipStream_t stream)
{
    const float* x  = (const float*)d_in[0];
    const float* Wq = (const float*)d_in[1];
    const float* bq = (const float*)d_in[2];
    const float* Wk = (const float*)d_in[3];
    const float* bk = (const float*)d_in[4];
    const float* Wv = (const float*)d_in[5];
    const float* bv = (const float*)d_in[6];
    const float* Wo = (const float*)d_in[7];
    const float* bo = (const float*)d_in[8];
    const float* gm = (const float*)d_in[9];
    const float* bt = (const float*)d_in[10];
    const float* mn = (const float*)d_in[11];
    const float* vr = (const float*)d_in[12];
    float* out = (float*)d_out;

    char* wsb = (char*)d_ws;
    __hip_bfloat16* qg  = (__hip_bfloat16*)(wsb);                      // 1 MB
    __hip_bfloat16* kg  = (__hip_bfloat16*)(wsb + (1u  << 20));        // 1 MB
    __hip_bfloat16* vg  = (__hip_bfloat16*)(wsb + (2u  << 20));        // 8 MB
    __hip_bfloat16* att = (__hip_bfloat16*)(wsb + (10u << 20));        // 8 MB (= ph1)
    __hip_bfloat16* Wt  = (__hip_bfloat16*)(wsb + (18u << 20));        // 1.2 MB
    __hip_bfloat16* xt  = (__hip_bfloat16*)(wsb + (20u << 20));        // 8 MB (= ph0 later)
    __hip_bfloat16* Wqk = (__hip_bfloat16*)(wsb + (28u << 20));        // 64 KB
    __hip_bfloat16* Wvb = (__hip_bfloat16*)(wsb + (28u << 20) + 65536);// 128 KB
    float*          Lh  = (float*)(wsb + (28u << 20) + 262144);        // 192 KB
    float*          Linv= (float*)(wsb + (28u << 20) + 458752);        // 64 KB
    __hip_bfloat16* ph2 = (__hip_bfloat16*)(wsb + (29u << 20));        // 8 MB -> 37 MB

    __hip_bfloat16* ph0 = xt;   // xt dead after projections (stream-ordered)
    __hip_bfloat16* ph1 = att;

    w_prep_kernel  <<<261,  256, 0, stream>>>(Wo, Wq, Wk, Wv, Wt, Wqk, Wvb);
    xt_prep_kernel <<<1024, 256, 0, stream>>>(x, xt);
    qk_mfma_kernel <<<256,  256, 0, stream>>>(xt, Wqk, bq, bk, qg, kg);
    v_mfma_kernel  <<<512,  256, 0, stream>>>(xt, Wvb, bv, vg);
    flash_kernel   <<<768,  256, 0, stream>>>(qg, kg, vg, ph0, ph1, ph2, Lh);
    linv_kernel    <<<64,   256, 0, stream>>>(Lh, Linv);
    conv_mfma_kernel<<<512, 256, 0, stream>>>(ph0, ph1, ph2, Linv, Wt, bo, gm, bt, mn, vr, x, out);
}

// Round 13
// 155.225 us; speedup vs baseline: 1.1531x; 1.1531x over previous
//
#include <hip/hip_runtime.h>
#include <hip/hip_bf16.h>
#include <math.h>

#define N_TOK 4096

typedef __attribute__((ext_vector_type(8))) short short8;
typedef __attribute__((ext_vector_type(4))) float f32x4;

#define MFMA16(a, b, c) __builtin_amdgcn_mfma_f32_16x16x32_bf16(a, b, c, 0, 0, 0)

__device__ inline unsigned pack_bf16x2(float a, float b) {
    __hip_bfloat16 ha = __float2bfloat16(a), hb = __float2bfloat16(b);
    unsigned short ua = *(unsigned short*)&ha, ub = *(unsigned short*)&hb;
    return (unsigned)ua | ((unsigned)ub << 16);
}

__device__ inline float bf2f(unsigned short u) {
    unsigned v = ((unsigned)u) << 16;
    union { unsigned u; float f; } cv; cv.u = v; return cv.f;
}

// swizzled 16B-chunk slot for row-stride-64B LDS tiles (<=2-way conflicts)
__device__ inline int swz4(int h, int row) { return (h ^ row ^ (row >> 2)) & 3; }

// scale * log2(e), folded into q at projection time
#define SCK 0.25506974748975505f

// ---------------------------------------------------------------------------
// Weight prep: Wo->Wt[tap][o][c] bf16 ; Wq,Wk->Wqk[64][256] ; Wv->Wvb bf16
// ---------------------------------------------------------------------------
__global__ __launch_bounds__(256) void w_prep_kernel(
    const float* __restrict__ Wo, const float* __restrict__ Wq,
    const float* __restrict__ Wk, const float* __restrict__ Wv,
    __hip_bfloat16* __restrict__ Wt, __hip_bfloat16* __restrict__ Wqk,
    __hip_bfloat16* __restrict__ Wvb)
{
    int blk = blockIdx.x, t = threadIdx.x;
    if (blk < 256) {
        const float* src = &Wo[(size_t)(blk * 256 + t) * 9];
#pragma unroll
        for (int tap = 0; tap < 9; ++tap)
            Wt[(size_t)(tap * 256 + blk) * 256 + t] = __float2bfloat16(src[tap]);
    } else if (blk < 260) {
        int r0 = (blk - 256) * 64;
        for (int r = r0; r < r0 + 64; ++r)
            Wvb[r * 256 + t] = __float2bfloat16(Wv[r * 256 + t]);
    } else {
        for (int r = 0; r < 32; ++r) {
            // q rows pre-scaled by SCK (softmax scale * log2e folded in)
            Wqk[r * 256 + t]        = __float2bfloat16(Wq[r * 256 + t] * SCK);
            Wqk[(r + 32) * 256 + t] = __float2bfloat16(Wk[r * 256 + t]);
        }
    }
}

// ---------------------------------------------------------------------------
// Fused QKV projection: reads x (B,C,N) f32 directly; per 64-c chunk stages
// a transposed bf16 tile in LDS (xt_prep-proven pattern, pad-72 rows), then
// MFMA: 4 qk m-tiles + 16 v m-tiles per wave. Eliminates the xt buffer.
// block = 64 n, grid = B*64 = 256.
// ---------------------------------------------------------------------------
__global__ __launch_bounds__(256) void qkv_kernel(
    const float* __restrict__ x,
    const __hip_bfloat16* __restrict__ Wqk, const __hip_bfloat16* __restrict__ Wvb,
    const float* __restrict__ bq, const float* __restrict__ bk,
    const float* __restrict__ bv,
    __hip_bfloat16* __restrict__ qg, __hip_bfloat16* __restrict__ kg,
    __hip_bfloat16* __restrict__ vg)
{
    __shared__ __hip_bfloat16 tl[64][72];   // [n][c-chunk] pad 8
    int blk = blockIdx.x;
    int b = blk >> 6, n0 = (blk & 63) * 64;
    int t = threadIdx.x, w = t >> 6, lane = t & 63;
    int l15 = lane & 15, l4 = lane >> 4;
    int n = n0 + w * 16 + l15;

    f32x4 zf = {0.f, 0.f, 0.f, 0.f};
    f32x4 aqk[4], av[16];
#pragma unroll
    for (int m = 0; m < 4; ++m) aqk[m] = zf;
#pragma unroll
    for (int m = 0; m < 16; ++m) av[m] = zf;

    int cr = t >> 4, part = t & 15;

    for (int cc = 0; cc < 256; cc += 64) {
        __syncthreads();
        // ---- stage 64c x 64n transposed -> tl (xt_prep pattern)
#pragma unroll
        for (int rep = 0; rep < 4; ++rep) {
            int c = rep * 16 + cr;
            float4 v4 = *(const float4*)&x[((size_t)(b * 256 + cc + c)) * N_TOK + n0 + part * 4];
            tl[part * 4 + 0][c] = __float2bfloat16(v4.x);
            tl[part * 4 + 1][c] = __float2bfloat16(v4.y);
            tl[part * 4 + 2][c] = __float2bfloat16(v4.z);
            tl[part * 4 + 3][c] = __float2bfloat16(v4.w);
        }
        __syncthreads();
        // ---- 2 k-windows of 32c
#pragma unroll
        for (int kk = 0; kk < 2; ++kk) {
            int k0 = cc + kk * 32;
            short8 bfr = *(const short8*)&tl[w * 16 + l15][kk * 32 + l4 * 8];
#pragma unroll
            for (int m = 0; m < 4; ++m) {
                short8 af = *(const short8*)&Wqk[(size_t)(m * 16 + l15) * 256 + k0 + l4 * 8];
                aqk[m] = MFMA16(af, bfr, aqk[m]);
            }
#pragma unroll
            for (int m = 0; m < 16; ++m) {
                short8 af = *(const short8*)&Wvb[(size_t)(m * 16 + l15) * 256 + k0 + l4 * 8];
                av[m] = MFMA16(af, bfr, av[m]);
            }
        }
    }

    // ---- qk epilogue (bq scaled by SCK; layout as before)
    f32x4 bq0 = *(const f32x4*)&bq[l4 * 4];
    f32x4 bq1 = *(const f32x4*)&bq[16 + l4 * 4];
    f32x4 bk0 = *(const f32x4*)&bk[l4 * 4];
    f32x4 bk1 = *(const f32x4*)&bk[16 + l4 * 4];
    size_t obase = (size_t)(b * N_TOK + n) * 32;
    uint2 u;
    u.x = pack_bf16x2(aqk[0][0] + bq0[0] * SCK, aqk[0][1] + bq0[1] * SCK);
    u.y = pack_bf16x2(aqk[0][2] + bq0[2] * SCK, aqk[0][3] + bq0[3] * SCK);
    *(uint2*)&qg[obase + l4 * 4] = u;
    u.x = pack_bf16x2(aqk[1][0] + bq1[0] * SCK, aqk[1][1] + bq1[1] * SCK);
    u.y = pack_bf16x2(aqk[1][2] + bq1[2] * SCK, aqk[1][3] + bq1[3] * SCK);
    *(uint2*)&qg[obase + 16 + l4 * 4] = u;
    u.x = pack_bf16x2(aqk[2][0] + bk0[0], aqk[2][1] + bk0[1]);
    u.y = pack_bf16x2(aqk[2][2] + bk0[2], aqk[2][3] + bk0[3]);
    *(uint2*)&kg[obase + l4 * 4] = u;
    u.x = pack_bf16x2(aqk[3][0] + bk1[0], aqk[3][1] + bk1[1]);
    u.y = pack_bf16x2(aqk[3][2] + bk1[2], aqk[3][3] + bk1[3]);
    *(uint2*)&kg[obase + 16 + l4 * 4] = u;

    // ---- v epilogue (B,C,N), 16 m-tiles
#pragma unroll
    for (int m = 0; m < 16; ++m) {
        int cb = m * 16 + l4 * 4;
        f32x4 bvv = *(const f32x4*)&bv[cb];
#pragma unroll
        for (int r = 0; r < 4; ++r)
            vg[((size_t)(b * 256 + cb + r)) * N_TOK + n] = __float2bfloat16(av[m][r] + bvv[r]);
    }
}

// ---------------------------------------------------------------------------
// Flash v8 (r11-proven, byte-identical): kh=2 key-split, wave = 32q x 128c,
// block = 4 waves, grid = 512 (2 blocks/CU). K staged in LDS (swz4), V dbuf,
// wave-private P. Bare-exp2 softmax (scale folded into q), unnormalized
// partials + per-(kh,b,n) L.
// ---------------------------------------------------------------------------
__global__ __launch_bounds__(256, 2) void flash_kernel(
    const __hip_bfloat16* __restrict__ qg, const __hip_bfloat16* __restrict__ kg,
    const __hip_bfloat16* __restrict__ vg,
    __hip_bfloat16* __restrict__ ph0, __hip_bfloat16* __restrict__ ph1,
    float* __restrict__ Lh)
{
    __shared__ __hip_bfloat16 v_lds[2][128 * 64];  // 32 KB [c][64k]
    __shared__ __hip_bfloat16 k_lds[2][64 * 32];   // 8 KB [key][32d]
    __shared__ __hip_bfloat16 p_lds[4][32 * 64];   // 16 KB wave-private [q][64k]

    int blk = blockIdx.x;
    int work = (blk & 7) * 64 + (blk >> 3);
    int g = work >> 6;
    int kh = g >> 2, cs = (g >> 1) & 1, bl = g & 1;
    int rem = work & 63;
    int b = ((rem >> 5) << 1) | bl;
    int qgp = rem & 31;
    int t = threadIdx.x, w = t >> 6, lane = t & 63;
    int l15 = lane & 15, l4 = lane >> 4;
    int qw = qgp * 128 + w * 32;

    short8 qf[2];
#pragma unroll
    for (int qs = 0; qs < 2; ++qs)
        qf[qs] = *(const short8*)&qg[((size_t)(b * N_TOK + qw + qs * 16 + l15)) * 32 + l4 * 8];

    f32x4 zf = {0.f, 0.f, 0.f, 0.f};
    f32x4 acc[2][8];
#pragma unroll
    for (int qs = 0; qs < 2; ++qs)
#pragma unroll
        for (int ct = 0; ct < 8; ++ct) acc[qs][ct] = zf;
    float Lr[2] = {0.f, 0.f};

    int vc  = t >> 1;
    int kb4 = (t & 1) * 4;
    int kr  = t >> 2;
    int kch = t & 3;

    const __hip_bfloat16* vrow  = &vg[((size_t)(b * 256 + cs * 128 + vc)) * N_TOK + kh * 2048];
    const __hip_bfloat16* kbase = &kg[((size_t)(b * N_TOK + kh * 2048)) * 32];

    uint4 vp[4], kp;

#pragma unroll
    for (int j = 0; j < 4; ++j)
        vp[j] = *(const uint4*)&vrow[(kb4 + j) * 8];
    kp = *(const uint4*)&kbase[kr * 32 + kch * 8];
#pragma unroll
    for (int j = 0; j < 4; ++j)
        *(uint4*)&v_lds[0][vc * 64 + (((2 * (kb4 + j)) ^ (vc & 14)) << 2)] = vp[j];
    *(uint4*)&k_lds[0][kr * 32 + swz4(kch, kr) * 8] = kp;
    __syncthreads();

    int buf = 0;
    for (int it = 0; it < 32; ++it) {
        int nm0 = it * 64 + 64;
        bool more = (it < 31);
        if (more) {
#pragma unroll
            for (int j = 0; j < 4; ++j)
                vp[j] = *(const uint4*)&vrow[nm0 + (kb4 + j) * 8];
            kp = *(const uint4*)&kbase[(size_t)(nm0 + kr) * 32 + kch * 8];
        }

        short8 kf[4];
#pragma unroll
        for (int kt = 0; kt < 4; ++kt) {
            int row = kt * 16 + l15;
            kf[kt] = *(const short8*)&k_lds[buf][row * 32 + swz4(l4, row) * 8];
        }
        f32x4 sf[2][4];
#pragma unroll
        for (int qs = 0; qs < 2; ++qs)
#pragma unroll
            for (int kt = 0; kt < 4; ++kt)
                sf[qs][kt] = MFMA16(kf[kt], qf[qs], zf);

        // ---- bare exp2 (scale folded into q; no shift needed)
#pragma unroll
        for (int qs = 0; qs < 2; ++qs) {
            int prow = qs * 16 + l15;
#pragma unroll
            for (int kt = 0; kt < 4; ++kt) {
                float p0 = exp2f(sf[qs][kt][0]);
                float p1 = exp2f(sf[qs][kt][1]);
                float p2 = exp2f(sf[qs][kt][2]);
                float p3 = exp2f(sf[qs][kt][3]);
                Lr[qs] += (p0 + p1) + (p2 + p3);
                uint2 u;
                u.x = pack_bf16x2(p0, p1);
                u.y = pack_bf16x2(p2, p3);
                *(uint2*)&p_lds[w][prow * 64 + (((kt * 4 + l4) ^ (l15 & 14)) << 2)] = u;
            }
        }

#pragma unroll
        for (int ks = 0; ks < 2; ++ks) {
            short8 pb[2];
#pragma unroll
            for (int qs = 0; qs < 2; ++qs)
                pb[qs] = *(const short8*)&p_lds[w][(qs * 16 + l15) * 64 +
                         (((ks * 8 + l4 * 2) ^ (l15 & 14)) << 2)];
#pragma unroll
            for (int ct = 0; ct < 8; ++ct) {
                int cr = ct * 16 + l15;
                short8 vf = *(const short8*)&v_lds[buf][cr * 64 +
                           (((ks * 8 + l4 * 2) ^ (cr & 14)) << 2)];
                acc[0][ct] = MFMA16(vf, pb[0], acc[0][ct]);
                acc[1][ct] = MFMA16(vf, pb[1], acc[1][ct]);
            }
        }

        if (more) {
#pragma unroll
            for (int j = 0; j < 4; ++j)
                *(uint4*)&v_lds[buf ^ 1][vc * 64 + (((2 * (kb4 + j)) ^ (vc & 14)) << 2)] = vp[j];
            *(uint4*)&k_lds[buf ^ 1][kr * 32 + swz4(kch, kr) * 8] = kp;
            buf ^= 1;
        }
        __syncthreads();
    }

#pragma unroll
    for (int qs = 0; qs < 2; ++qs) {
        float L = Lr[qs];
        L += __shfl_xor(L, 16);
        L += __shfl_xor(L, 32);
        int nq = qw + qs * 16 + l15;
        if (cs == 0 && l4 == 0)
            Lh[kh * 16384 + b * 4096 + nq] = L;
        __hip_bfloat16* pdst = kh ? ph1 : ph0;
        size_t pix = (size_t)(b * N_TOK + nq);
#pragma unroll
        for (int ct = 0; ct < 8; ++ct) {
            int cl = cs * 128 + ct * 16 + l4 * 4;
            uint2 u;
            u.x = pack_bf16x2(acc[qs][ct][0], acc[qs][ct][1]);
            u.y = pack_bf16x2(acc[qs][ct][2], acc[qs][ct][3]);
            *(uint2*)&pdst[pix * 256 + cl] = u;
        }
    }
}

// ---------------------------------------------------------------------------
// Implicit-GEMM 3x3 conv via MFMA + bias + BN + ReLU + residual.
// Spatial tile 16x8 (grid 512). Staging fuses the partial-combine with
// inline Linv: att = (ph0 + ph1) / (Lh0 + Lh1).
// ---------------------------------------------------------------------------
__global__ __launch_bounds__(256) void conv_mfma_kernel(
    const __hip_bfloat16* __restrict__ ph0, const __hip_bfloat16* __restrict__ ph1,
    const float* __restrict__ Lh, const __hip_bfloat16* __restrict__ Wt,
    const float* __restrict__ bo,  const float* __restrict__ gamma,
    const float* __restrict__ beta, const float* __restrict__ mean,
    const float* __restrict__ var, const float* __restrict__ x,
    float* __restrict__ out)
{
    __shared__ __hip_bfloat16 in_lds[180 * 32];     // [10x18 halo][32c] swz
    __shared__ __hip_bfloat16 wt_lds[9 * 64 * 32];  // [tap][o64][32c] swz

    int blk = blockIdx.x;
    int sp = blk & 31, ob = (blk >> 5) & 3, b = blk >> 7;
    int y0 = (sp >> 2) * 8, x0 = (sp & 3) * 16;
    int o0 = ob * 64;
    int t = threadIdx.x;
    int w = t >> 6, lane = t & 63;
    int l15 = lane & 15, l4 = lane >> 4;

    f32x4 zf = {0.f, 0.f, 0.f, 0.f};
    f32x4 acc[4][2];   // [m][ntw]
#pragma unroll
    for (int m = 0; m < 4; ++m)
#pragma unroll
        for (int n = 0; n < 2; ++n) acc[m][n] = zf;

    for (int cc = 0; cc < 256; cc += 32) {
        __syncthreads();
        for (int jj = t; jj < 720; jj += 256) {
            int pix = jj >> 2, h = jj & 3;
            int iy = pix / 18, ix = pix - iy * 18;
            int gy = y0 - 1 + iy, gx = x0 - 1 + ix;
            uint4 val = {0u, 0u, 0u, 0u};
            if (gy >= 0 && gy < 64 && gx >= 0 && gx < 64) {
                int bn = b * 4096 + gy * 64 + gx;
                float inv = 1.f / (Lh[bn] + Lh[16384 + bn]);
                size_t e = (size_t)bn * 256 + cc + h * 8;
                uint4 a  = *(const uint4*)&ph0[e];
                uint4 b4 = *(const uint4*)&ph1[e];
                const unsigned* ap = (const unsigned*)&a;
                const unsigned* bp = (const unsigned*)&b4;
                unsigned* vpn = (unsigned*)&val;
#pragma unroll
                for (int j = 0; j < 4; ++j) {
                    float lo = (bf2f((unsigned short)(ap[j] & 0xffff)) +
                                bf2f((unsigned short)(bp[j] & 0xffff))) * inv;
                    float hi = (bf2f((unsigned short)(ap[j] >> 16)) +
                                bf2f((unsigned short)(bp[j] >> 16))) * inv;
                    vpn[j] = pack_bf16x2(lo, hi);
                }
            }
            *(uint4*)&in_lds[pix * 32 + swz4(h, pix) * 8] = val;
        }
        for (int jj = t; jj < 2304; jj += 256) {
            int tap = jj >> 8, rem = jj & 255;
            int o = rem >> 2, h = rem & 3;
            uint4 wv = *(const uint4*)&Wt[((size_t)(tap * 256 + o0 + o)) * 256 + cc + h * 8];
            *(uint4*)&wt_lds[tap * 2048 + o * 32 + swz4(h, o) * 8] = wv;
        }
        __syncthreads();

#pragma unroll
        for (int ky = 0; ky < 3; ++ky) {
#pragma unroll
            for (int kx = 0; kx < 3; ++kx) {
                int tap = ky * 3 + kx;
                short8 af[4];
#pragma unroll
                for (int m = 0; m < 4; ++m) {
                    int orow = m * 16 + l15;
                    af[m] = *(const short8*)&wt_lds[tap * 2048 + orow * 32 + swz4(l4, orow) * 8];
                }
#pragma unroll
                for (int ntw = 0; ntw < 2; ++ntw) {
                    int yy = w * 2 + ntw;
                    int p = (yy + ky) * 18 + kx + l15;
                    short8 bfr = *(const short8*)&in_lds[p * 32 + swz4(l4, p) * 8];
#pragma unroll
                    for (int m = 0; m < 4; ++m)
                        acc[m][ntw] = MFMA16(af[m], bfr, acc[m][ntw]);
                }
            }
        }
    }

#pragma unroll
    for (int m = 0; m < 4; ++m) {
#pragma unroll
        for (int r = 0; r < 4; ++r) {
            int oc = o0 + m * 16 + l4 * 4 + r;
            float inv = gamma[oc] * rsqrtf(var[oc] + 1e-5f);
            float sh  = (bo[oc] - mean[oc]) * inv + beta[oc];
#pragma unroll
            for (int ntw = 0; ntw < 2; ++ntw) {
                int gy = y0 + w * 2 + ntw, gx = x0 + l15;
                size_t idx = (size_t)(b * 256 + oc) * 4096 + (size_t)gy * 64 + gx;
                float yv = acc[m][ntw][r] * inv + sh;
                yv = fmaxf(yv, 0.f);
                out[idx] = yv + x[idx];
            }
        }
    }
}

// ---------------------------------------------------------------------------
extern "C" void kernel_launch(void* const* d_in, const int* in_sizes, int n_in,
                              void* d_out, int out_size, void* d_ws, size_t ws_size,
                              hipStream_t stream)
{
    const float* x  = (const float*)d_in[0];
    const float* Wq = (const float*)d_in[1];
    const float* bq = (const float*)d_in[2];
    const float* Wk = (const float*)d_in[3];
    const float* bk = (const float*)d_in[4];
    const float* Wv = (const float*)d_in[5];
    const float* bv = (const float*)d_in[6];
    const float* Wo = (const float*)d_in[7];
    const float* bo = (const float*)d_in[8];
    const float* gm = (const float*)d_in[9];
    const float* bt = (const float*)d_in[10];
    const float* mn = (const float*)d_in[11];
    const float* vr = (const float*)d_in[12];
    float* out = (float*)d_out;

    char* wsb = (char*)d_ws;
    __hip_bfloat16* qg  = (__hip_bfloat16*)(wsb);                      // 1 MB
    __hip_bfloat16* kg  = (__hip_bfloat16*)(wsb + (1u  << 20));        // 1 MB
    __hip_bfloat16* vg  = (__hip_bfloat16*)(wsb + (2u  << 20));        // 8 MB
    __hip_bfloat16* ph1 = (__hip_bfloat16*)(wsb + (10u << 20));        // 8 MB
    __hip_bfloat16* Wt  = (__hip_bfloat16*)(wsb + (18u << 20));        // 1.2 MB
    __hip_bfloat16* ph0 = (__hip_bfloat16*)(wsb + (20u << 20));        // 8 MB
    __hip_bfloat16* Wqk = (__hip_bfloat16*)(wsb + (28u << 20));        // 32 KB
    __hip_bfloat16* Wvb = (__hip_bfloat16*)(wsb + (28u << 20) + 65536);// 128 KB
    float*          Lh  = (float*)(wsb + (28u << 20) + 262144);        // 128 KB

    w_prep_kernel  <<<261,  256, 0, stream>>>(Wo, Wq, Wk, Wv, Wt, Wqk, Wvb);
    qkv_kernel     <<<256,  256, 0, stream>>>(x, Wqk, Wvb, bq, bk, bv, qg, kg, vg);
    flash_kernel   <<<512,  256, 0, stream>>>(qg, kg, vg, ph0, ph1, Lh);
    conv_mfma_kernel<<<512, 256, 0, stream>>>(ph0, ph1, Lh, Wt, bo, gm, bt, mn, vr, x, out);
}